// Round 5
// baseline (1925.636 us; speedup 1.0000x reference)
//
#include <hip/hip_runtime.h>
#include <stdint.h>

// ---------------------------------------------------------------------------
// RNN: S=512, B=64, IN=512, HID=1024, OUT=512, keep=0.7
//   Xh   = x @ Wihx^T + b_i2h                       (gemm_bt, bf16 out)
//   h_t  = Xh_t + h_{t-1} @ Whh^T                   (scan_mega + correct)
//   oc   = x@U1^T + h_prev@U2^T + h_new@Wo2^T + b'  (gemm_fused, fp32, *mask)
//          where U1=Wo1·Wiox, U2=Wo1·Wioh, b'=Wo1·b_i2o+b_o2o
//   d_out = log_softmax(oc)                         (softmax, in-place)
//
// scan_mega: grid=256 (1 block/CU residency GUARANTEED at any VGPR count ->
// flag barrier cannot deadlock; round-4's 512-block version hung).
//   s0: copy Harr[8c+1]=Xh[8c] (64 jobs) || W2 (64 jobs)
//   s1..s7: pass1 step k (256 jobs) + power ride-alongs (2nd job per block)
//   s8..s13: Hillis-Steele over chunk starts (256 jobs, W^8..W^256)
// correct_kernel (round-3-proven, plain launch): Harr[8c+j] += S_c@(W^j)^T.
// ---------------------------------------------------------------------------

typedef unsigned short ushort_t;
typedef __attribute__((ext_vector_type(8))) __bf16 bf16x8;
typedef __attribute__((ext_vector_type(4))) float f32x4;

__device__ __forceinline__ ushort_t f2bf(float f) {
  union { float f; uint32_t u; } v; v.f = f;
  uint32_t r = v.u + 0x7fffu + ((v.u >> 16) & 1u);   // RNE
  return (ushort_t)(r >> 16);
}
__device__ __forceinline__ float bf2f(ushort_t b) {
  union { uint32_t u; float f; } v; v.u = ((uint32_t)b) << 16;
  return v.f;
}
__device__ __forceinline__ void gload16(const ushort_t* g, ushort_t* l) {
  __builtin_amdgcn_global_load_lds(
      (const __attribute__((address_space(1))) uint32_t*)g,
      (__attribute__((address_space(3))) uint32_t*)l, 16, 0, 0);
}

// ---------------------------------------------------------------- init -----
__global__ __launch_bounds__(256) void init_kernel(uint32_t* harr0, int* cnt) {
  int i = blockIdx.x * blockDim.x + threadIdx.x;
  if (i < 32768) harr0[i] = 0;        // Harr slot 0 = h_0 = 0
  if (i < 16) cnt[i] = 0;             // grid-barrier counters
}

// ---------------------------------------------------------------- pack -----
__global__ __launch_bounds__(256) void pack_kernel(
    const float* __restrict__ x, const float* __restrict__ W_i2h,
    const float* __restrict__ W_i2o, const float* __restrict__ W_o2o,
    const float* __restrict__ b_i2o, const float* __restrict__ b_o2o,
    ushort_t* xB, ushort_t* Wihx, ushort_t* Whh, ushort_t* Wiox,
    ushort_t* Wioh, ushort_t* Wo1, ushort_t* Wo2, float* biasP) {
  int64_t i = (int64_t)blockIdx.x * blockDim.x + threadIdx.x;
  const int64_t c0 = 16777216, c1 = 17301504, c2 = 18350080, c3 = 18612224,
                c4 = 19136512, c5 = 19398656, c6 = 19922944, c7 = 19923456;
  if (i < c0) { xB[i] = f2bf(x[i]); return; }
  if (i < c1) { int64_t j = i - c0; int r = j >> 9,  c = j & 511;  Wihx[j] = f2bf(W_i2h[(int64_t)r * 1536 + c]); return; }
  if (i < c2) { int64_t j = i - c1; int r = j >> 10, c = j & 1023; Whh[j]  = f2bf(W_i2h[(int64_t)r * 1536 + 512 + c]); return; }
  if (i < c3) { int64_t j = i - c2; int r = j >> 9,  c = j & 511;  Wiox[j] = f2bf(W_i2o[(int64_t)r * 1536 + c]); return; }
  if (i < c4) { int64_t j = i - c3; int r = j >> 10, c = j & 1023; Wioh[j] = f2bf(W_i2o[(int64_t)r * 1536 + 512 + c]); return; }
  if (i < c5) { int64_t j = i - c4; int r = j >> 9,  c = j & 511;  Wo1[j]  = f2bf(W_o2o[(int64_t)r * 1536 + c]); return; }
  if (i < c6) { int64_t j = i - c5; int r = j >> 10, c = j & 1023; Wo2[j]  = f2bf(W_o2o[(int64_t)r * 1536 + 512 + c]); return; }
  if (i < c7) {                       // bias' (fp32, exact)
    int n = (int)(i - c6);
    const float* wr = W_o2o + (int64_t)n * 1536;
    float s = 0.f;
    for (int m = 0; m < 512; ++m) s += wr[m] * b_i2o[m];
    biasP[n] = s + b_o2o[n];
  }
}

// ---------------------------------------------------------------- GEMM -----
// Xh GEMM: C[32768,1024] = A1@B1^T + bias (bf16 out). mt=bid&255 -> same-A
// blocks 256 apart in dispatch order (same XCD round-robin slot).
__global__ __launch_bounds__(256) void gemm_bt(
    const ushort_t* __restrict__ A1, int lda1, const ushort_t* __restrict__ B1, int K1,
    const float* __restrict__ bias, ushort_t* Cb, int Ntiles) {
  __shared__ __align__(16) ushort_t AsF[4096];
  __shared__ __align__(16) ushort_t BsF[4096];
  const int mt = blockIdx.x & 255, nt = blockIdx.x >> 8;
  const int m0 = mt * 128, n0 = nt * 128;
  const int tid = threadIdx.x;
  const int w = tid >> 6, l = tid & 63;
  const int quad = l >> 4, l15 = l & 15;
  const int wm = (w & 1) * 64, wn = (w >> 1) * 64;
  const int r0 = tid >> 2, chunk = tid & 3;
  f32x4 acc[4][4] = {};
  for (int k0 = 0; k0 < K1; k0 += 32) {
    __syncthreads();
    gload16(A1 + (size_t)(m0 + r0) * lda1 + k0 + chunk * 8,      &AsF[tid * 8]);
    gload16(A1 + (size_t)(m0 + r0 + 64) * lda1 + k0 + chunk * 8, &AsF[2048 + tid * 8]);
    gload16(B1 + (size_t)(n0 + r0) * K1 + k0 + chunk * 8,        &BsF[tid * 8]);
    gload16(B1 + (size_t)(n0 + r0 + 64) * K1 + k0 + chunk * 8,   &BsF[2048 + tid * 8]);
    __syncthreads();
    bf16x8 af[4], bfr[4];
#pragma unroll
    for (int i = 0; i < 4; ++i) af[i]  = *(const bf16x8*)&AsF[(wm + 16 * i + l15) * 32 + 8 * quad];
#pragma unroll
    for (int j = 0; j < 4; ++j) bfr[j] = *(const bf16x8*)&BsF[(wn + 16 * j + l15) * 32 + 8 * quad];
#pragma unroll
    for (int i = 0; i < 4; ++i)
#pragma unroll
      for (int j = 0; j < 4; ++j)
        acc[i][j] = __builtin_amdgcn_mfma_f32_16x16x32_bf16(af[i], bfr[j], acc[i][j], 0, 0, 0);
  }
  const int N = Ntiles * 128;
#pragma unroll
  for (int i = 0; i < 4; ++i) {
    const int row = m0 + wm + 16 * i + 4 * quad;
#pragma unroll
    for (int j = 0; j < 4; ++j) {
      const int col = n0 + wn + 16 * j + l15;
      const float bv = bias[col];
#pragma unroll
      for (int r = 0; r < 4; ++r)
        Cb[(size_t)(row + r) * N + col] = f2bf(acc[i][j][r] + bv);
    }
  }
}

// -------------------------------------------------------------- usetup -----
// U1 = Wo1·Wiox [512,512], U2 = Wo1·Wioh [512,1024]. 48 blocks, K=512.
__global__ __launch_bounds__(256) void usetup_kernel(
    const ushort_t* __restrict__ Wo1, const ushort_t* __restrict__ Wiox,
    const ushort_t* __restrict__ Wioh, ushort_t* __restrict__ U1,
    ushort_t* __restrict__ U2) {
  __shared__ __align__(16) ushort_t AsF[4096];
  __shared__ __align__(16) ushort_t BsF[4096];
  int job = blockIdx.x;
  const ushort_t* Bm; ushort_t* Om; int mt, nt, ldb;
  if (job < 16) { mt = job >> 2; nt = job & 3; Bm = Wiox; Om = U1; ldb = 512; }
  else { job -= 16; mt = job >> 3; nt = job & 7; Bm = Wioh; Om = U2; ldb = 1024; }
  const int m0 = mt * 128, n0 = nt * 128;
  const int tid = threadIdx.x;
  const int w = tid >> 6, l = tid & 63;
  const int quad = l >> 4, l15 = l & 15;
  const int wm = (w & 1) * 64, wn = (w >> 1) * 64;
  const int r0 = tid >> 2, chunk = tid & 3;
  f32x4 acc[4][4] = {};
  for (int k0 = 0; k0 < 512; k0 += 32) {
    __syncthreads();
    gload16(Wo1 + (size_t)(m0 + r0) * 512 + k0 + chunk * 8,      &AsF[tid * 8]);
    gload16(Wo1 + (size_t)(m0 + r0 + 64) * 512 + k0 + chunk * 8, &AsF[2048 + tid * 8]);
#pragma unroll
    for (int rep = 0; rep < 2; ++rep) {
      const int idx = tid + 256 * rep;
      const int kk = idx & 31, n8 = idx >> 5;
      union { uint4 v; ushort_t s[8]; } u;
      u.v = *(const uint4*)(Bm + (size_t)(k0 + kk) * ldb + n0 + n8 * 8);
#pragma unroll
      for (int i = 0; i < 8; ++i) BsF[(n8 * 8 + i) * 32 + kk] = u.s[i];
    }
    __syncthreads();
    bf16x8 af[4], bfr[4];
#pragma unroll
    for (int i = 0; i < 4; ++i) af[i]  = *(const bf16x8*)&AsF[(wm + 16 * i + l15) * 32 + 8 * quad];
#pragma unroll
    for (int j = 0; j < 4; ++j) bfr[j] = *(const bf16x8*)&BsF[(wn + 16 * j + l15) * 32 + 8 * quad];
#pragma unroll
    for (int i = 0; i < 4; ++i)
#pragma unroll
      for (int j = 0; j < 4; ++j)
        acc[i][j] = __builtin_amdgcn_mfma_f32_16x16x32_bf16(af[i], bfr[j], acc[i][j], 0, 0, 0);
  }
#pragma unroll
  for (int i = 0; i < 4; ++i) {
    const int row = m0 + wm + 16 * i + 4 * quad;
#pragma unroll
    for (int j = 0; j < 4; ++j) {
      const int col = n0 + wn + 16 * j + l15;
#pragma unroll
      for (int r = 0; r < 4; ++r)
        Om[(size_t)(row + r) * ldb + col] = f2bf(acc[i][j][r]);
    }
  }
}

// ----------------------------------------------------------- tile_job ------
// 128x128 tile, K=1024. a0/a1: 64-row halves (ld 1024). B: !btr -> [N,1024]
// row-major; btr -> [1024,1024] plain, transposed into LDS. x0/x1: optional
// bf16 add; per-half gate zeroes the GEMM term.
__device__ void tile_job(
    const ushort_t* a0, const ushort_t* a1,
    const ushort_t* B, int btr, int n0,
    const ushort_t* x0, const ushort_t* x1,
    ushort_t* o0, ushort_t* o1, int g0, int g1) {
  __shared__ __align__(16) ushort_t AsF[4096];
  __shared__ __align__(16) ushort_t BsF[4096];
  const int tid = threadIdx.x;
  const int w = tid >> 6, l = tid & 63;
  const int quad = l >> 4, l15 = l & 15;
  const int wm = (w & 1) * 64, wn = (w >> 1) * 64;
  const int r0 = tid >> 2, chunk = tid & 3;
  f32x4 acc[4][4] = {};
  for (int k0 = 0; k0 < 1024; k0 += 32) {
    __syncthreads();
    gload16(a0 + (size_t)r0 * 1024 + k0 + chunk * 8, &AsF[tid * 8]);
    gload16(a1 + (size_t)r0 * 1024 + k0 + chunk * 8, &AsF[2048 + tid * 8]);
    if (!btr) {
      gload16(B + (size_t)(n0 + r0) * 1024 + k0 + chunk * 8,      &BsF[tid * 8]);
      gload16(B + (size_t)(n0 + r0 + 64) * 1024 + k0 + chunk * 8, &BsF[2048 + tid * 8]);
    } else {
#pragma unroll
      for (int rep = 0; rep < 2; ++rep) {
        const int idx = tid + 256 * rep;
        const int kk = idx & 31, n8 = idx >> 5;
        union { uint4 v; ushort_t s[8]; } u;
        u.v = *(const uint4*)(B + (size_t)(k0 + kk) * 1024 + n0 + n8 * 8);
#pragma unroll
        for (int i = 0; i < 8; ++i) BsF[(n8 * 8 + i) * 32 + kk] = u.s[i];
      }
    }
    __syncthreads();
    bf16x8 af[4], bfr[4];
#pragma unroll
    for (int i = 0; i < 4; ++i) af[i]  = *(const bf16x8*)&AsF[(wm + 16 * i + l15) * 32 + 8 * quad];
#pragma unroll
    for (int j = 0; j < 4; ++j) bfr[j] = *(const bf16x8*)&BsF[(wn + 16 * j + l15) * 32 + 8 * quad];
#pragma unroll
    for (int i = 0; i < 4; ++i)
#pragma unroll
      for (int j = 0; j < 4; ++j)
        acc[i][j] = __builtin_amdgcn_mfma_f32_16x16x32_bf16(af[i], bfr[j], acc[i][j], 0, 0, 0);
  }
#pragma unroll
  for (int i = 0; i < 4; ++i) {
#pragma unroll
    for (int j = 0; j < 4; ++j) {
      const int col = n0 + wn + 16 * j + l15;
#pragma unroll
      for (int r = 0; r < 4; ++r) {
        const int gr = wm + 16 * i + 4 * quad + r;
        const int half = gr >> 6, rr = gr & 63;
        float v = (half ? g1 : g0) ? acc[i][j][r] : 0.0f;
        const ushort_t* xx = half ? x1 : x0;
        if (xx) v += bf2f(xx[(size_t)rr * 1024 + col]);
        (half ? o1 : o0)[(size_t)rr * 1024 + col] = f2bf(v);
      }
    }
  }
}

// device-scope grid barrier; grid is EXACTLY 256 blocks (1/CU residency is
// guaranteed for 256-thread 16KB-LDS blocks at ANY VGPR count -> no deadlock).
__device__ __forceinline__ void gsync(int* cnt, int s) {
  __threadfence();
  __syncthreads();
  if (threadIdx.x == 0) {
    atomicAdd(&cnt[s], 1);
    while (__hip_atomic_load(&cnt[s], __ATOMIC_RELAXED, __HIP_MEMORY_SCOPE_AGENT) < 256) {}
  }
  __syncthreads();
  __threadfence();
}

#define PWp(idx) (Pw + (size_t)(idx) * 1048576)
// slots: 0:W2 1:W3 2:W4 3:W5 4:W6 5:W7 6:W8 7:W16 8:W32 9:W64 10:W128 11:W256

__global__ __launch_bounds__(256) void scan_mega(
    const ushort_t* __restrict__ XhB, ushort_t* __restrict__ Harr,
    ushort_t* __restrict__ Pw, ushort_t* __restrict__ SA,
    ushort_t* __restrict__ SB, const ushort_t* __restrict__ Whh,
    int* __restrict__ cnt) {
  const int bid = blockIdx.x;   // 0..255
  const int tid = threadIdx.x;

  // ---- s0: copy Harr[8c+1] = Xh[8c]  ||  W2 = W·W
  if (bid < 64) {
    const ushort_t* src = XhB + (size_t)bid * 524288;
    ushort_t* dst = Harr + 65536 + (size_t)bid * 524288;
#pragma unroll
    for (int it = 0; it < 32; ++it)
      *(uint4*)(dst + it * 2048 + tid * 8) = *(const uint4*)(src + it * 2048 + tid * 8);
  } else if (bid < 128) {
    const int t = bid - 64, mt = t >> 3, nt = t & 7;
    const ushort_t* a0 = Whh + (size_t)mt * 131072;
    tile_job(a0, a0 + 65536, Whh, 1, nt * 128, nullptr, nullptr,
             PWp(0) + (size_t)mt * 131072, PWp(0) + (size_t)mt * 131072 + 65536, 1, 1);
  }
  gsync(cnt, 0);

  // ---- s1..s7: pass1 step k (256 jobs) + power ride-along (2nd job)
  for (int k = 1; k <= 7; ++k) {
    {
      const int p = bid & 31, nt = bid >> 5;
      const size_t c0 = (size_t)(2 * p) * 524288, c1 = c0 + 524288;
      tile_job(Harr + (size_t)k * 65536 + c0, Harr + (size_t)k * 65536 + c1,
               Whh, 0, nt * 128,
               XhB + (size_t)k * 65536 + c0, XhB + (size_t)k * 65536 + c1,
               Harr + (size_t)(k + 1) * 65536 + c0,
               Harr + (size_t)(k + 1) * 65536 + c1, 1, 1);
    }
    {
      const ushort_t *A = nullptr, *Bp = nullptr; ushort_t* O = nullptr;
      const int pj = bid >> 6, t = bid & 63;
      if (k == 1) {
        if (pj == 0)      { A = Whh;    Bp = PWp(0); O = PWp(1); }   // W3
        else if (pj == 1) { A = PWp(0); Bp = PWp(0); O = PWp(2); }   // W4
      } else if (k == 2) {
        if (pj == 0)      { A = Whh;    Bp = PWp(2); O = PWp(3); }   // W5
        else if (pj == 1) { A = PWp(0); Bp = PWp(2); O = PWp(4); }   // W6
        else if (pj == 2) { A = PWp(1); Bp = PWp(2); O = PWp(5); }   // W7
        else              { A = PWp(2); Bp = PWp(2); O = PWp(6); }   // W8
      } else if (pj == 0) {  // k=3..7: W16,W32,W64,W128,W256
        A = PWp(3 + k); Bp = A; O = PWp(4 + k);
      }
      if (A) {
        const int mt = t >> 3, nt2 = t & 7;
        tile_job(A + (size_t)mt * 131072, A + (size_t)mt * 131072 + 65536,
                 Bp, 1, nt2 * 128, nullptr, nullptr,
                 O + (size_t)mt * 131072, O + (size_t)mt * 131072 + 65536, 1, 1);
      }
    }
    gsync(cnt, k);
  }

  // ---- s8..s13: Hillis-Steele scan (d = 1,2,4,8,16,32) -> final S in SA
  for (int si = 0; si < 6; ++si) {
    const int d = 1 << si;
    const ushort_t* oldB; size_t oldStr; ushort_t* nw;
    if (si == 0)      { oldB = Harr; oldStr = 524288; nw = SB; }
    else if (si & 1)  { oldB = SB;   oldStr = 65536;  nw = SA; }
    else              { oldB = SA;   oldStr = 65536;  nw = SB; }
    const int p = bid & 31, nt = bid >> 5;
    const int ca = 2 * p, cb = ca + 1;
    const int ia = ca >= d ? ca - d : ca, ib = cb >= d ? cb - d : cb;
    tile_job(oldB + (size_t)ia * oldStr, oldB + (size_t)ib * oldStr,
             PWp(6 + si), 0, nt * 128,
             oldB + (size_t)ca * oldStr, oldB + (size_t)cb * oldStr,
             nw + (size_t)ca * 65536, nw + (size_t)cb * 65536,
             ca >= d, cb >= d);
    if (si < 5) gsync(cnt, 8 + si);
  }
}

// ----------------------------------------------------------- correction ----
// Round-3-proven. grid (256, 8): j = blockIdx.y+1:
//   Harr[8c+j] += S[c] @ (W^j)^T   for all 64 chunks c.
__global__ __launch_bounds__(256) void correct_kernel(
    const ushort_t* __restrict__ S, ushort_t* __restrict__ Harr,
    const ushort_t* __restrict__ B1, const ushort_t* __restrict__ B2,
    const ushort_t* __restrict__ B3, const ushort_t* __restrict__ B4,
    const ushort_t* __restrict__ B5, const ushort_t* __restrict__ B6,
    const ushort_t* __restrict__ B7, const ushort_t* __restrict__ B8) {
  __shared__ __align__(16) ushort_t AsF[4096];
  __shared__ __align__(16) ushort_t BsF[4096];
  const int p = blockIdx.x >> 3;
  const int n0 = (blockIdx.x & 7) * 128;
  const int j = blockIdx.y + 1;
  const ushort_t* Wj;
  switch (j) {
    case 1: Wj = B1; break; case 2: Wj = B2; break;
    case 3: Wj = B3; break; case 4: Wj = B4; break;
    case 5: Wj = B5; break; case 6: Wj = B6; break;
    case 7: Wj = B7; break; default: Wj = B8; break;
  }
  ushort_t* XO = Harr + (size_t)j * 65536;
  const int tid = threadIdx.x;
  const int w = tid >> 6, l = tid & 63;
  const int quad = l >> 4, l15 = l & 15;
  const int wm = (w & 1) * 64, wn = (w >> 1) * 64;
  const int r0 = tid >> 2, chunk = tid & 3;
  f32x4 acc[4][4] = {};
  const ushort_t* a0 = S + (size_t)(2 * p) * 65536 + (size_t)r0 * 1024;
  const ushort_t* a1 = S + (size_t)(2 * p + 1) * 65536 + (size_t)r0 * 1024;
  for (int k0 = 0; k0 < 1024; k0 += 32) {
    __syncthreads();
    gload16(a0 + k0 + chunk * 8, &AsF[tid * 8]);
    gload16(a1 + k0 + chunk * 8, &AsF[2048 + tid * 8]);
    gload16(Wj + (size_t)(n0 + r0) * 1024 + k0 + chunk * 8,      &BsF[tid * 8]);
    gload16(Wj + (size_t)(n0 + r0 + 64) * 1024 + k0 + chunk * 8, &BsF[2048 + tid * 8]);
    __syncthreads();
    bf16x8 af[4], bfr[4];
#pragma unroll
    for (int i = 0; i < 4; ++i) af[i]  = *(const bf16x8*)&AsF[(wm + 16 * i + l15) * 32 + 8 * quad];
#pragma unroll
    for (int jj = 0; jj < 4; ++jj) bfr[jj] = *(const bf16x8*)&BsF[(wn + 16 * jj + l15) * 32 + 8 * quad];
#pragma unroll
    for (int i = 0; i < 4; ++i)
#pragma unroll
      for (int jj = 0; jj < 4; ++jj)
        acc[i][jj] = __builtin_amdgcn_mfma_f32_16x16x32_bf16(af[i], bfr[jj], acc[i][jj], 0, 0, 0);
  }
#pragma unroll
  for (int i = 0; i < 4; ++i) {
#pragma unroll
    for (int jj = 0; jj < 4; ++jj) {
      const int col = n0 + wn + 16 * jj + l15;
#pragma unroll
      for (int r = 0; r < 4; ++r) {
        const int gr = wm + 16 * i + 4 * quad + r;
        const int c = 2 * p + (gr >> 6);
        const size_t idx = (size_t)c * 524288 + (size_t)(gr & 63) * 1024 + col;
        XO[idx] = f2bf(acc[i][jj][r] + bf2f(XO[idx]));
      }
    }
  }
}

// ---------------------------------------------------------- fused final ----
// oc = xB@U1^T + Hprev@U2^T + Hnew@Wo2^T + bias' ; out = oc * mask (fp32)
__global__ __launch_bounds__(256) void gemm_fused(
    const ushort_t* __restrict__ xB, const ushort_t* __restrict__ U1,
    const ushort_t* __restrict__ Harr, const ushort_t* __restrict__ U2,
    const ushort_t* __restrict__ Wo2, const float* __restrict__ biasP,
    const float* __restrict__ mask, float* __restrict__ out) {
  __shared__ __align__(16) ushort_t AsF[4096];
  __shared__ __align__(16) ushort_t BsF[4096];
  const int mt = blockIdx.x & 255, nt = blockIdx.x >> 8;
  const int m0 = mt * 128, n0 = nt * 128;
  const int tid = threadIdx.x;
  const int w = tid >> 6, l = tid & 63;
  const int quad = l >> 4, l15 = l & 15;
  const int wm = (w & 1) * 64, wn = (w >> 1) * 64;
  const int r0 = tid >> 2, chunk = tid & 3;
  f32x4 acc[4][4] = {};
  for (int ph = 0; ph < 3; ++ph) {
    const ushort_t* A = ph == 0 ? xB : (ph == 1 ? Harr : Harr + 65536);
    const ushort_t* B = ph == 0 ? U1 : (ph == 1 ? U2 : Wo2);
    const int K = ph == 0 ? 512 : 1024;
    for (int k0 = 0; k0 < K; k0 += 32) {
      __syncthreads();
      gload16(A + (size_t)(m0 + r0) * K + k0 + chunk * 8,      &AsF[tid * 8]);
      gload16(A + (size_t)(m0 + r0 + 64) * K + k0 + chunk * 8, &AsF[2048 + tid * 8]);
      gload16(B + (size_t)(n0 + r0) * K + k0 + chunk * 8,      &BsF[tid * 8]);
      gload16(B + (size_t)(n0 + r0 + 64) * K + k0 + chunk * 8, &BsF[2048 + tid * 8]);
      __syncthreads();
      bf16x8 af[4], bfr[4];
#pragma unroll
      for (int i = 0; i < 4; ++i) af[i]  = *(const bf16x8*)&AsF[(wm + 16 * i + l15) * 32 + 8 * quad];
#pragma unroll
      for (int j = 0; j < 4; ++j) bfr[j] = *(const bf16x8*)&BsF[(wn + 16 * j + l15) * 32 + 8 * quad];
#pragma unroll
      for (int i = 0; i < 4; ++i)
#pragma unroll
        for (int j = 0; j < 4; ++j)
          acc[i][j] = __builtin_amdgcn_mfma_f32_16x16x32_bf16(af[i], bfr[j], acc[i][j], 0, 0, 0);
    }
  }
#pragma unroll
  for (int i = 0; i < 4; ++i) {
    const int row = m0 + wm + 16 * i + 4 * quad;
#pragma unroll
    for (int j = 0; j < 4; ++j) {
      const int col = n0 + wn + 16 * j + l15;
      const float bv = biasP[col];
#pragma unroll
      for (int r = 0; r < 4; ++r) {
        const size_t idx = (size_t)(row + r) * 512 + col;
        out[idx] = (acc[i][j][r] + bv) * mask[idx];
      }
    }
  }
}

// -------------------------------------------------------------- softmax ----
__global__ __launch_bounds__(256) void softmax_kernel(float* __restrict__ out) {
  const int row = blockIdx.x;
  const int tid = threadIdx.x;
  const size_t base = (size_t)row * 512;
  __shared__ float sm[4], ss[4];
  const float v0 = out[base + tid];
  const float v1 = out[base + tid + 256];
  float m = fmaxf(v0, v1);
#pragma unroll
  for (int off = 32; off; off >>= 1) m = fmaxf(m, __shfl_xor(m, off, 64));
  const int w = tid >> 6;
  if ((tid & 63) == 0) sm[w] = m;
  __syncthreads();
  m = fmaxf(fmaxf(sm[0], sm[1]), fmaxf(sm[2], sm[3]));
  float s = __expf(v0 - m) + __expf(v1 - m);
#pragma unroll
  for (int off = 32; off; off >>= 1) s += __shfl_xor(s, off, 64);
  if ((tid & 63) == 0) ss[w] = s;
  __syncthreads();
  s = ss[0] + ss[1] + ss[2] + ss[3];
  const float lg = logf(s);
  out[base + tid] = v0 - m - lg;
  out[base + tid + 256] = v1 - m - lg;
}

// ---------------------------------------------------------------------------
extern "C" void kernel_launch(void* const* d_in, const int* in_sizes, int n_in,
                              void* d_out, int out_size, void* d_ws, size_t ws_size,
                              hipStream_t stream) {
  const float* x     = (const float*)d_in[0];
  const float* mask  = (const float*)d_in[1];
  const float* W_i2h = (const float*)d_in[2];
  const float* b_i2h = (const float*)d_in[3];
  const float* W_i2o = (const float*)d_in[4];
  const float* b_i2o = (const float*)d_in[5];
  const float* W_o2o = (const float*)d_in[6];
  const float* b_o2o = (const float*)d_in[7];
  float* out = (float*)d_out;

  char* ws = (char*)d_ws;
  const size_t NEED = 207753216;
  if (ws_size < NEED) return;
  ushort_t* xB   = (ushort_t*)(ws + 0);            // [32768,512] bf16
  ushort_t* XhB  = (ushort_t*)(ws + 33554432);     // [512][64,1024] bf16
  // SA/SB overlay XhB chunks 0..15 (fully consumed by pass1 before scan)
  ushort_t* SA   = (ushort_t*)(ws + 33554432);     // [64][64,1024]
  ushort_t* SB   = (ushort_t*)(ws + 41943040);     // [64][64,1024]
  ushort_t* Harr = (ushort_t*)(ws + 100663296);    // [513][64,1024] bf16
  ushort_t* Pw   = (ushort_t*)(ws + 167903232);    // 12 x [1024,1024] powers
  ushort_t* U1   = (ushort_t*)(ws + 193069056);    // [512,512]
  ushort_t* U2   = (ushort_t*)(ws + 193593344);    // [512,1024]
  float* biasP   = (float*)(ws + 194641920);       // [512] fp32
  ushort_t* Wihx = (ushort_t*)(ws + 201457664);
  ushort_t* Whh  = (ushort_t*)(ws + 202506240);
  ushort_t* Wiox = (ushort_t*)(ws + 204603392);
  ushort_t* Wioh = (ushort_t*)(ws + 205127680);
  ushort_t* Wo1  = (ushort_t*)(ws + 206176256);
  ushort_t* Wo2  = (ushort_t*)(ws + 206700544);
  int* cnt       = (int*)(ws + 207749120);

  hipLaunchKernelGGL(init_kernel, dim3(128), dim3(256), 0, stream,
                     (uint32_t*)Harr, cnt);
  hipLaunchKernelGGL(pack_kernel, dim3(77826), dim3(256), 0, stream,
                     x, W_i2h, W_i2o, W_o2o, b_i2o, b_o2o,
                     xB, Wihx, Whh, Wiox, Wioh, Wo1, Wo2, biasP);
  hipLaunchKernelGGL(gemm_bt, dim3(2048), dim3(256), 0, stream,
                     xB, 512, Wihx, 512, b_i2h, XhB, 8);
  hipLaunchKernelGGL(usetup_kernel, dim3(48), dim3(256), 0, stream,
                     Wo1, Wiox, Wioh, U1, U2);
  // copy + pass1 + powers + Hillis-Steele (grid 256: residency guaranteed)
  hipLaunchKernelGGL(scan_mega, dim3(256), dim3(256), 0, stream,
                     XhB, Harr, Pw, SA, SB, Whh, cnt);
  // correction: Harr[8c+j] += S_c @ (W^j)^T, j=1..8
  hipLaunchKernelGGL(correct_kernel, dim3(dim3(256, 8)), dim3(256), 0, stream,
                     SA, Harr,
                     Whh, Pw, Pw + 1048576, Pw + 2097152, Pw + 3145728,
                     Pw + 4194304, Pw + 5242880, Pw + 6291456);
  // oc = xB@U1^T + Hprev@U2^T + Hnew@Wo2^T + bias', *mask -> d_out
  hipLaunchKernelGGL(gemm_fused, dim3(1024), dim3(256), 0, stream,
                     xB, U1, Harr, U2, Wo2, biasP, mask, out);
  hipLaunchKernelGGL(softmax_kernel, dim3(32768), dim3(256), 0, stream, out);
}

// Round 6
// 1090.653 us; speedup vs baseline: 1.7656x; 1.7656x over previous
//
#include <hip/hip_runtime.h>
#include <stdint.h>

// ---------------------------------------------------------------------------
// RNN: S=512, B=64, IN=512, HID=1024, OUT=512, keep=0.7
//   Xh   = x @ Wihx^T + b_i2h                       (gemm_bt, bf16 out)
//   h_t  = Xh_t + h_{t-1} @ Whh^T                   (launch-based chunked scan)
//   oc   = x@U1^T + h_prev@U2^T + h_new@Wo2^T + b'  (gemm_fused, fp32, *mask)
//   d_out = log_softmax(oc)                         (softmax, in-place)
//
// NO grid barriers (round-5 lesson: spin barrier + device fences invalidate
// per-XCD L2 every stage -> 281MB refetch, 4% MfmaUtil). Plain launches:
//   pass1 k=1..7: step_pow (512 step blocks, 64x128 dbuf tiles, 2 blocks/CU)
//                 + power-product ride-along blocks (dep-ordered)
//   scan d=1..32: scan64 (512 blocks), SA/SB = slot-1/slot-3 overlays of XhB
//   correction:   correct_kernel (round-3-proven), j=1 reads XhB slot 0
// ---------------------------------------------------------------------------

typedef unsigned short ushort_t;
typedef __attribute__((ext_vector_type(8))) __bf16 bf16x8;
typedef __attribute__((ext_vector_type(4))) float f32x4;

__device__ __forceinline__ ushort_t f2bf(float f) {
  union { float f; uint32_t u; } v; v.f = f;
  uint32_t r = v.u + 0x7fffu + ((v.u >> 16) & 1u);   // RNE
  return (ushort_t)(r >> 16);
}
__device__ __forceinline__ float bf2f(ushort_t b) {
  union { uint32_t u; float f; } v; v.u = ((uint32_t)b) << 16;
  return v.f;
}
__device__ __forceinline__ void gload16(const ushort_t* g, ushort_t* l) {
  __builtin_amdgcn_global_load_lds(
      (const __attribute__((address_space(1))) uint32_t*)g,
      (__attribute__((address_space(3))) uint32_t*)l, 16, 0, 0);
}

// ---------------------------------------------------------------- init -----
__global__ __launch_bounds__(256) void init_kernel(uint32_t* harr0) {
  int i = blockIdx.x * blockDim.x + threadIdx.x;
  if (i < 32768) harr0[i] = 0;        // Harr slot 0 = h_0 = 0
}

// ---------------------------------------------------------------- pack -----
__global__ __launch_bounds__(256) void pack_kernel(
    const float* __restrict__ x, const float* __restrict__ W_i2h,
    const float* __restrict__ W_i2o, const float* __restrict__ W_o2o,
    const float* __restrict__ b_i2o, const float* __restrict__ b_o2o,
    ushort_t* xB, ushort_t* Wihx, ushort_t* Whh, ushort_t* Wiox,
    ushort_t* Wioh, ushort_t* Wo1, ushort_t* Wo2, float* biasP) {
  int64_t i = (int64_t)blockIdx.x * blockDim.x + threadIdx.x;
  const int64_t c0 = 16777216, c1 = 17301504, c2 = 18350080, c3 = 18612224,
                c4 = 19136512, c5 = 19398656, c6 = 19922944, c7 = 19923456;
  if (i < c0) { xB[i] = f2bf(x[i]); return; }
  if (i < c1) { int64_t j = i - c0; int r = j >> 9,  c = j & 511;  Wihx[j] = f2bf(W_i2h[(int64_t)r * 1536 + c]); return; }
  if (i < c2) { int64_t j = i - c1; int r = j >> 10, c = j & 1023; Whh[j]  = f2bf(W_i2h[(int64_t)r * 1536 + 512 + c]); return; }
  if (i < c3) { int64_t j = i - c2; int r = j >> 9,  c = j & 511;  Wiox[j] = f2bf(W_i2o[(int64_t)r * 1536 + c]); return; }
  if (i < c4) { int64_t j = i - c3; int r = j >> 10, c = j & 1023; Wioh[j] = f2bf(W_i2o[(int64_t)r * 1536 + 512 + c]); return; }
  if (i < c5) { int64_t j = i - c4; int r = j >> 9,  c = j & 511;  Wo1[j]  = f2bf(W_o2o[(int64_t)r * 1536 + c]); return; }
  if (i < c6) { int64_t j = i - c5; int r = j >> 10, c = j & 1023; Wo2[j]  = f2bf(W_o2o[(int64_t)r * 1536 + 512 + c]); return; }
  if (i < c7) {                       // bias' = Wo1·b_i2o + b_o2o (fp32 exact)
    int n = (int)(i - c6);
    const float* wr = W_o2o + (int64_t)n * 1536;
    float s = 0.f;
    for (int m = 0; m < 512; ++m) s += wr[m] * b_i2o[m];
    biasP[n] = s + b_o2o[n];
  }
}

// ---------------------------------------------------------------- GEMM -----
// Xh: C[32768,1024] = A1@B1^T + bias (bf16 out). XCD-friendly decode.
__global__ __launch_bounds__(256) void gemm_bt(
    const ushort_t* __restrict__ A1, int lda1, const ushort_t* __restrict__ B1, int K1,
    const float* __restrict__ bias, ushort_t* Cb, int Ntiles) {
  __shared__ __align__(16) ushort_t AsF[4096];
  __shared__ __align__(16) ushort_t BsF[4096];
  const int mt = blockIdx.x & 255, nt = blockIdx.x >> 8;
  const int m0 = mt * 128, n0 = nt * 128;
  const int tid = threadIdx.x;
  const int w = tid >> 6, l = tid & 63;
  const int quad = l >> 4, l15 = l & 15;
  const int wm = (w & 1) * 64, wn = (w >> 1) * 64;
  const int r0 = tid >> 2, chunk = tid & 3;
  f32x4 acc[4][4] = {};
  for (int k0 = 0; k0 < K1; k0 += 32) {
    __syncthreads();
    gload16(A1 + (size_t)(m0 + r0) * lda1 + k0 + chunk * 8,      &AsF[tid * 8]);
    gload16(A1 + (size_t)(m0 + r0 + 64) * lda1 + k0 + chunk * 8, &AsF[2048 + tid * 8]);
    gload16(B1 + (size_t)(n0 + r0) * K1 + k0 + chunk * 8,        &BsF[tid * 8]);
    gload16(B1 + (size_t)(n0 + r0 + 64) * K1 + k0 + chunk * 8,   &BsF[2048 + tid * 8]);
    __syncthreads();
    bf16x8 af[4], bfr[4];
#pragma unroll
    for (int i = 0; i < 4; ++i) af[i]  = *(const bf16x8*)&AsF[(wm + 16 * i + l15) * 32 + 8 * quad];
#pragma unroll
    for (int j = 0; j < 4; ++j) bfr[j] = *(const bf16x8*)&BsF[(wn + 16 * j + l15) * 32 + 8 * quad];
#pragma unroll
    for (int i = 0; i < 4; ++i)
#pragma unroll
      for (int j = 0; j < 4; ++j)
        acc[i][j] = __builtin_amdgcn_mfma_f32_16x16x32_bf16(af[i], bfr[j], acc[i][j], 0, 0, 0);
  }
  const int N = Ntiles * 128;
#pragma unroll
  for (int i = 0; i < 4; ++i) {
    const int row = m0 + wm + 16 * i + 4 * quad;
#pragma unroll
    for (int j = 0; j < 4; ++j) {
      const int col = n0 + wn + 16 * j + l15;
      const float bv = bias[col];
#pragma unroll
      for (int r = 0; r < 4; ++r)
        Cb[(size_t)(row + r) * N + col] = f2bf(acc[i][j][r] + bv);
    }
  }
}

// -------------------------------------------------------------- usetup -----
// U1 = Wo1·Wiox [512,512], U2 = Wo1·Wioh [512,1024]. 48 blocks, K=512.
__global__ __launch_bounds__(256) void usetup_kernel(
    const ushort_t* __restrict__ Wo1, const ushort_t* __restrict__ Wiox,
    const ushort_t* __restrict__ Wioh, ushort_t* __restrict__ U1,
    ushort_t* __restrict__ U2) {
  __shared__ __align__(16) ushort_t AsF[4096];
  __shared__ __align__(16) ushort_t BsF[4096];
  int job = blockIdx.x;
  const ushort_t* Bm; ushort_t* Om; int mt, nt, ldb;
  if (job < 16) { mt = job >> 2; nt = job & 3; Bm = Wiox; Om = U1; ldb = 512; }
  else { job -= 16; mt = job >> 3; nt = job & 7; Bm = Wioh; Om = U2; ldb = 1024; }
  const int m0 = mt * 128, n0 = nt * 128;
  const int tid = threadIdx.x;
  const int w = tid >> 6, l = tid & 63;
  const int quad = l >> 4, l15 = l & 15;
  const int wm = (w & 1) * 64, wn = (w >> 1) * 64;
  const int r0 = tid >> 2, chunk = tid & 3;
  f32x4 acc[4][4] = {};
  for (int k0 = 0; k0 < 512; k0 += 32) {
    __syncthreads();
    gload16(Wo1 + (size_t)(m0 + r0) * 512 + k0 + chunk * 8,      &AsF[tid * 8]);
    gload16(Wo1 + (size_t)(m0 + r0 + 64) * 512 + k0 + chunk * 8, &AsF[2048 + tid * 8]);
#pragma unroll
    for (int rep = 0; rep < 2; ++rep) {
      const int idx = tid + 256 * rep;
      const int kk = idx & 31, n8 = idx >> 5;
      union { uint4 v; ushort_t s[8]; } u;
      u.v = *(const uint4*)(Bm + (size_t)(k0 + kk) * ldb + n0 + n8 * 8);
#pragma unroll
      for (int i = 0; i < 8; ++i) BsF[(n8 * 8 + i) * 32 + kk] = u.s[i];
    }
    __syncthreads();
    bf16x8 af[4], bfr[4];
#pragma unroll
    for (int i = 0; i < 4; ++i) af[i]  = *(const bf16x8*)&AsF[(wm + 16 * i + l15) * 32 + 8 * quad];
#pragma unroll
    for (int j = 0; j < 4; ++j) bfr[j] = *(const bf16x8*)&BsF[(wn + 16 * j + l15) * 32 + 8 * quad];
#pragma unroll
    for (int i = 0; i < 4; ++i)
#pragma unroll
      for (int j = 0; j < 4; ++j)
        acc[i][j] = __builtin_amdgcn_mfma_f32_16x16x32_bf16(af[i], bfr[j], acc[i][j], 0, 0, 0);
  }
#pragma unroll
  for (int i = 0; i < 4; ++i) {
    const int row = m0 + wm + 16 * i + 4 * quad;
#pragma unroll
    for (int j = 0; j < 4; ++j) {
      const int col = n0 + wn + 16 * j + l15;
#pragma unroll
      for (int r = 0; r < 4; ++r)
        Om[(size_t)(row + r) * ldb + col] = f2bf(acc[i][j][r]);
    }
  }
}

// ---------------------------------------------------------- step tile ------
// 64 rows (one chunk) x 128 cols, K=1024, double-buffered LDS.
// O = gate?(A@B^T):0 + X.  B row-major [N,1024]. 4 waves = 4 col-bands of 32.
__device__ void step_tile64(
    const ushort_t* __restrict__ A, const ushort_t* __restrict__ B, int n0,
    const ushort_t* __restrict__ X, ushort_t* __restrict__ O, int gate) {
  __shared__ __align__(16) ushort_t As[2][2048];   // [64][32]
  __shared__ __align__(16) ushort_t Bs[2][4096];   // [128][32]
  const int tid = threadIdx.x;
  const int w = tid >> 6, l = tid & 63;
  const int quad = l >> 4, l15 = l & 15;
  const int r0 = tid >> 2, chunk = tid & 3;
  f32x4 acc[4][2] = {};
  // preload k0 = 0 into buffer 0
  gload16(A + (size_t)r0 * 1024 + chunk * 8,             &As[0][tid * 8]);
  gload16(B + (size_t)(n0 + r0) * 1024 + chunk * 8,      &Bs[0][tid * 8]);
  gload16(B + (size_t)(n0 + r0 + 64) * 1024 + chunk * 8, &Bs[0][2048 + tid * 8]);
  for (int k0 = 0; k0 < 32; ++k0) {
    const int p = k0 & 1;
    __syncthreads();              // drains buf[p] loads; protects buf[p^1] reuse
    if (k0 < 31) {
      const int kn = (k0 + 1) * 32;
      gload16(A + (size_t)r0 * 1024 + kn + chunk * 8,             &As[p ^ 1][tid * 8]);
      gload16(B + (size_t)(n0 + r0) * 1024 + kn + chunk * 8,      &Bs[p ^ 1][tid * 8]);
      gload16(B + (size_t)(n0 + r0 + 64) * 1024 + kn + chunk * 8, &Bs[p ^ 1][2048 + tid * 8]);
    }
    bf16x8 af[4], bfr[2];
#pragma unroll
    for (int i = 0; i < 4; ++i) af[i]  = *(const bf16x8*)&As[p][(16 * i + l15) * 32 + 8 * quad];
#pragma unroll
    for (int j = 0; j < 2; ++j) bfr[j] = *(const bf16x8*)&Bs[p][(32 * w + 16 * j + l15) * 32 + 8 * quad];
#pragma unroll
    for (int i = 0; i < 4; ++i)
#pragma unroll
      for (int j = 0; j < 2; ++j)
        acc[i][j] = __builtin_amdgcn_mfma_f32_16x16x32_bf16(af[i], bfr[j], acc[i][j], 0, 0, 0);
  }
#pragma unroll
  for (int i = 0; i < 4; ++i) {
#pragma unroll
    for (int j = 0; j < 2; ++j) {
      const int col = n0 + 32 * w + 16 * j + l15;
#pragma unroll
      for (int r = 0; r < 4; ++r) {
        const int row = 16 * i + 4 * quad + r;
        const size_t idx = (size_t)row * 1024 + col;
        float v = gate ? acc[i][j][r] : 0.0f;
        O[idx] = f2bf(v + bf2f(X[idx]));
      }
    }
  }
}

// --------------------------------------------------------- power tile ------
// 128x128 tile of Om = Am @ Bm (plain [1024,1024] product, B^T into LDS).
__device__ void power_tile(const ushort_t* __restrict__ Am,
                           const ushort_t* __restrict__ Bm,
                           ushort_t* __restrict__ Om, int t) {
  __shared__ __align__(16) ushort_t AsF[4096];
  __shared__ __align__(16) ushort_t BsF[4096];
  const int mt = t >> 3, nt = t & 7;
  const int m0 = mt * 128, n0 = nt * 128;
  const int tid = threadIdx.x;
  const int w = tid >> 6, l = tid & 63;
  const int quad = l >> 4, l15 = l & 15;
  const int wm = (w & 1) * 64, wn = (w >> 1) * 64;
  const int r0 = tid >> 2, chunk = tid & 3;
  f32x4 acc[4][4] = {};
  for (int k0 = 0; k0 < 1024; k0 += 32) {
    __syncthreads();
    gload16(Am + (size_t)(m0 + r0) * 1024 + k0 + chunk * 8,      &AsF[tid * 8]);
    gload16(Am + (size_t)(m0 + r0 + 64) * 1024 + k0 + chunk * 8, &AsF[2048 + tid * 8]);
#pragma unroll
    for (int rep = 0; rep < 2; ++rep) {
      const int idx = tid + 256 * rep;
      const int kk = idx & 31, n8 = idx >> 5;
      union { uint4 v; ushort_t s[8]; } u;
      u.v = *(const uint4*)(Bm + (size_t)(k0 + kk) * 1024 + n0 + n8 * 8);
#pragma unroll
      for (int i = 0; i < 8; ++i) BsF[(n8 * 8 + i) * 32 + kk] = u.s[i];
    }
    __syncthreads();
    bf16x8 af[4], bfr[4];
#pragma unroll
    for (int i = 0; i < 4; ++i) af[i]  = *(const bf16x8*)&AsF[(wm + 16 * i + l15) * 32 + 8 * quad];
#pragma unroll
    for (int j = 0; j < 4; ++j) bfr[j] = *(const bf16x8*)&BsF[(wn + 16 * j + l15) * 32 + 8 * quad];
#pragma unroll
    for (int i = 0; i < 4; ++i)
#pragma unroll
      for (int j = 0; j < 4; ++j)
        acc[i][j] = __builtin_amdgcn_mfma_f32_16x16x32_bf16(af[i], bfr[j], acc[i][j], 0, 0, 0);
  }
#pragma unroll
  for (int i = 0; i < 4; ++i) {
    const int row = m0 + wm + 16 * i + 4 * quad;
#pragma unroll
    for (int j = 0; j < 4; ++j) {
      const int col = n0 + wn + 16 * j + l15;
#pragma unroll
      for (int r = 0; r < 4; ++r)
        Om[(size_t)(row + r) * 1024 + col] = f2bf(acc[i][j][r]);
    }
  }
}

#define PWp(idx) (Pw + (size_t)(idx) * 1048576)
// Pw slots: 0:W2 1:W3 2:W4 3:W5 4:W6 5:W7 6:W8 7:W16 8:W32 9:W64 10:W128 11:W256

// ------------------------------------------------------------ step_pow -----
// bid < 512 (mode 1..7): pass1 step. O[c] = X[c] + A[c]@Whh^T (strides 524288).
// bid >= 512 (or mode 8): power-product ride-along, dep-ordered by mode.
__global__ __launch_bounds__(256) void step_pow(
    const ushort_t* __restrict__ A, const ushort_t* __restrict__ X,
    ushort_t* __restrict__ O, const ushort_t* __restrict__ Whh,
    ushort_t* __restrict__ Pw, int mode) {
  const int bid = blockIdx.x;
  if (mode == 8 || bid >= 512) {
    const int q = (mode == 8) ? bid : bid - 512;
    const int pj = q >> 6, t = q & 63;
    const ushort_t *Am, *Bm; ushort_t* Om;
    switch (mode) {
      case 1:  Am = Whh;     Bm = Whh;     Om = PWp(0);  break;      // W2
      case 2:  if (pj == 0) { Am = Whh;    Bm = PWp(0);  Om = PWp(1); }   // W3
               else         { Am = PWp(0); Bm = PWp(0);  Om = PWp(2); }   // W4
               break;
      case 3:  if (pj == 0)      { Am = Whh;    Bm = PWp(2); Om = PWp(3); } // W5
               else if (pj == 1) { Am = PWp(0); Bm = PWp(2); Om = PWp(4); } // W6
               else if (pj == 2) { Am = PWp(1); Bm = PWp(2); Om = PWp(5); } // W7
               else              { Am = PWp(2); Bm = PWp(2); Om = PWp(6); } // W8
               break;
      case 4:  Am = PWp(6);  Bm = PWp(6);  Om = PWp(7);  break;      // W16
      case 5:  Am = PWp(7);  Bm = PWp(7);  Om = PWp(8);  break;      // W32
      case 6:  Am = PWp(8);  Bm = PWp(8);  Om = PWp(9);  break;      // W64
      case 7:  Am = PWp(9);  Bm = PWp(9);  Om = PWp(10); break;      // W128
      default: Am = PWp(10); Bm = PWp(10); Om = PWp(11); break;      // W256
    }
    power_tile(Am, Bm, Om, t);
    return;
  }
  const int c = bid >> 3, nt = bid & 7;
  step_tile64(A + (size_t)c * 524288, Whh, nt * 128,
              X + (size_t)c * 524288, O + (size_t)c * 524288, 1);
}

// -------------------------------------------------------------- scan64 -----
// nw[c] = old[c] + (c>=d ? old[c-d]@Pv^T : 0). All chunk strides 524288.
__global__ __launch_bounds__(256) void scan64(
    const ushort_t* __restrict__ old, ushort_t* __restrict__ nw,
    const ushort_t* __restrict__ Pv, int d) {
  const int c = blockIdx.x >> 3, nt = blockIdx.x & 7;
  const int ia = (c >= d) ? (c - d) : c;
  step_tile64(old + (size_t)ia * 524288, Pv, nt * 128,
              old + (size_t)c * 524288, nw + (size_t)c * 524288, c >= d);
}

// ----------------------------------------------------------- correction ----
// Round-3-proven body. grid (256, 8): j = blockIdx.y+1:
//   Harr[slot j][c] = X_j[c] + S[c]@(W^j)^T, X_1 = XhB slot0, X_j = slot j.
__global__ __launch_bounds__(256) void correct_kernel(
    const ushort_t* __restrict__ S, const ushort_t* __restrict__ XhB,
    ushort_t* __restrict__ Harr, const ushort_t* __restrict__ Whh,
    const ushort_t* __restrict__ Pw) {
  __shared__ __align__(16) ushort_t AsF[4096];
  __shared__ __align__(16) ushort_t BsF[4096];
  const int p = blockIdx.x >> 3;
  const int n0 = (blockIdx.x & 7) * 128;
  const int j = blockIdx.y + 1;
  const ushort_t* Wj = (j == 1) ? Whh : (Pw + (size_t)(j - 2) * 1048576);
  const ushort_t* Xs = (j == 1) ? XhB : (Harr + (size_t)j * 65536);
  ushort_t* XO = Harr + (size_t)j * 65536;
  const int tid = threadIdx.x;
  const int w = tid >> 6, l = tid & 63;
  const int quad = l >> 4, l15 = l & 15;
  const int wm = (w & 1) * 64, wn = (w >> 1) * 64;
  const int r0 = tid >> 2, chunk = tid & 3;
  f32x4 acc[4][4] = {};
  const ushort_t* a0 = S + (size_t)(2 * p) * 524288 + (size_t)r0 * 1024;
  const ushort_t* a1 = S + (size_t)(2 * p + 1) * 524288 + (size_t)r0 * 1024;
  for (int k0 = 0; k0 < 1024; k0 += 32) {
    __syncthreads();
    gload16(a0 + k0 + chunk * 8, &AsF[tid * 8]);
    gload16(a1 + k0 + chunk * 8, &AsF[2048 + tid * 8]);
    gload16(Wj + (size_t)(n0 + r0) * 1024 + k0 + chunk * 8,      &BsF[tid * 8]);
    gload16(Wj + (size_t)(n0 + r0 + 64) * 1024 + k0 + chunk * 8, &BsF[2048 + tid * 8]);
    __syncthreads();
    bf16x8 af[4], bfr[4];
#pragma unroll
    for (int i = 0; i < 4; ++i) af[i]  = *(const bf16x8*)&AsF[(wm + 16 * i + l15) * 32 + 8 * quad];
#pragma unroll
    for (int jj = 0; jj < 4; ++jj) bfr[jj] = *(const bf16x8*)&BsF[(wn + 16 * jj + l15) * 32 + 8 * quad];
#pragma unroll
    for (int i = 0; i < 4; ++i)
#pragma unroll
      for (int jj = 0; jj < 4; ++jj)
        acc[i][jj] = __builtin_amdgcn_mfma_f32_16x16x32_bf16(af[i], bfr[jj], acc[i][jj], 0, 0, 0);
  }
#pragma unroll
  for (int i = 0; i < 4; ++i) {
#pragma unroll
    for (int jj = 0; jj < 4; ++jj) {
      const int col = n0 + wn + 16 * jj + l15;
#pragma unroll
      for (int r = 0; r < 4; ++r) {
        const int gr = wm + 16 * i + 4 * quad + r;
        const int c = 2 * p + (gr >> 6);
        const size_t idx = (size_t)c * 524288 + (size_t)(gr & 63) * 1024 + col;
        XO[idx] = f2bf(acc[i][jj][r] + bf2f(Xs[idx]));
      }
    }
  }
}

// ---------------------------------------------------------- fused final ----
// oc = xB@U1^T + Hprev@U2^T + Hnew@Wo2^T + bias' ; out = oc * mask (fp32)
__global__ __launch_bounds__(256) void gemm_fused(
    const ushort_t* __restrict__ xB, const ushort_t* __restrict__ U1,
    const ushort_t* __restrict__ Harr, const ushort_t* __restrict__ U2,
    const ushort_t* __restrict__ Wo2, const float* __restrict__ biasP,
    const float* __restrict__ mask, float* __restrict__ out) {
  __shared__ __align__(16) ushort_t AsF[4096];
  __shared__ __align__(16) ushort_t BsF[4096];
  const int mt = blockIdx.x & 255, nt = blockIdx.x >> 8;
  const int m0 = mt * 128, n0 = nt * 128;
  const int tid = threadIdx.x;
  const int w = tid >> 6, l = tid & 63;
  const int quad = l >> 4, l15 = l & 15;
  const int wm = (w & 1) * 64, wn = (w >> 1) * 64;
  const int r0 = tid >> 2, chunk = tid & 3;
  f32x4 acc[4][4] = {};
  for (int ph = 0; ph < 3; ++ph) {
    const ushort_t* A = ph == 0 ? xB : (ph == 1 ? Harr : Harr + 65536);
    const ushort_t* B = ph == 0 ? U1 : (ph == 1 ? U2 : Wo2);
    const int K = ph == 0 ? 512 : 1024;
    for (int k0 = 0; k0 < K; k0 += 32) {
      __syncthreads();
      gload16(A + (size_t)(m0 + r0) * K + k0 + chunk * 8,      &AsF[tid * 8]);
      gload16(A + (size_t)(m0 + r0 + 64) * K + k0 + chunk * 8, &AsF[2048 + tid * 8]);
      gload16(B + (size_t)(n0 + r0) * K + k0 + chunk * 8,      &BsF[tid * 8]);
      gload16(B + (size_t)(n0 + r0 + 64) * K + k0 + chunk * 8, &BsF[2048 + tid * 8]);
      __syncthreads();
      bf16x8 af[4], bfr[4];
#pragma unroll
      for (int i = 0; i < 4; ++i) af[i]  = *(const bf16x8*)&AsF[(wm + 16 * i + l15) * 32 + 8 * quad];
#pragma unroll
      for (int j = 0; j < 4; ++j) bfr[j] = *(const bf16x8*)&BsF[(wn + 16 * j + l15) * 32 + 8 * quad];
#pragma unroll
      for (int i = 0; i < 4; ++i)
#pragma unroll
        for (int j = 0; j < 4; ++j)
          acc[i][j] = __builtin_amdgcn_mfma_f32_16x16x32_bf16(af[i], bfr[j], acc[i][j], 0, 0, 0);
    }
  }
#pragma unroll
  for (int i = 0; i < 4; ++i) {
    const int row = m0 + wm + 16 * i + 4 * quad;
#pragma unroll
    for (int j = 0; j < 4; ++j) {
      const int col = n0 + wn + 16 * j + l15;
      const float bv = biasP[col];
#pragma unroll
      for (int r = 0; r < 4; ++r) {
        const size_t idx = (size_t)(row + r) * 512 + col;
        out[idx] = (acc[i][j][r] + bv) * mask[idx];
      }
    }
  }
}

// -------------------------------------------------------------- softmax ----
__global__ __launch_bounds__(256) void softmax_kernel(float* __restrict__ out) {
  const int row = blockIdx.x;
  const int tid = threadIdx.x;
  const size_t base = (size_t)row * 512;
  __shared__ float sm[4], ss[4];
  const float v0 = out[base + tid];
  const float v1 = out[base + tid + 256];
  float m = fmaxf(v0, v1);
#pragma unroll
  for (int off = 32; off; off >>= 1) m = fmaxf(m, __shfl_xor(m, off, 64));
  const int w = tid >> 6;
  if ((tid & 63) == 0) sm[w] = m;
  __syncthreads();
  m = fmaxf(fmaxf(sm[0], sm[1]), fmaxf(sm[2], sm[3]));
  float s = __expf(v0 - m) + __expf(v1 - m);
#pragma unroll
  for (int off = 32; off; off >>= 1) s += __shfl_xor(s, off, 64);
  if ((tid & 63) == 0) ss[w] = s;
  __syncthreads();
  s = ss[0] + ss[1] + ss[2] + ss[3];
  const float lg = logf(s);
  out[base + tid] = v0 - m - lg;
  out[base + tid + 256] = v1 - m - lg;
}

// ---------------------------------------------------------------------------
extern "C" void kernel_launch(void* const* d_in, const int* in_sizes, int n_in,
                              void* d_out, int out_size, void* d_ws, size_t ws_size,
                              hipStream_t stream) {
  const float* x     = (const float*)d_in[0];
  const float* mask  = (const float*)d_in[1];
  const float* W_i2h = (const float*)d_in[2];
  const float* b_i2h = (const float*)d_in[3];
  const float* W_i2o = (const float*)d_in[4];
  const float* b_i2o = (const float*)d_in[5];
  const float* W_o2o = (const float*)d_in[6];
  const float* b_o2o = (const float*)d_in[7];
  float* out = (float*)d_out;

  char* ws = (char*)d_ws;
  const size_t NEED = 207749120;
  if (ws_size < NEED) return;
  ushort_t* xB   = (ushort_t*)(ws + 0);            // [32768,512] bf16
  ushort_t* XhB  = (ushort_t*)(ws + 33554432);     // [64 chunks][8 slots][64,1024]
  // SA/SB: strided overlays of XhB slots 1 / 3 (slots 1..7 dead after pass1;
  // slot 0 stays live for correction j=1). Chunk stride 524288.
  ushort_t* SA   = XhB + 65536;
  ushort_t* SB   = XhB + 3 * 65536;
  ushort_t* Harr = (ushort_t*)(ws + 100663296);    // [513][64,1024] bf16
  ushort_t* Pw   = (ushort_t*)(ws + 167903232);    // 12 x [1024,1024] powers
  ushort_t* U1   = (ushort_t*)(ws + 193069056);    // [512,512]
  ushort_t* U2   = (ushort_t*)(ws + 193593344);    // [512,1024]
  float* biasP   = (float*)(ws + 194641920);       // [512] fp32
  ushort_t* Wihx = (ushort_t*)(ws + 201457664);
  ushort_t* Whh  = (ushort_t*)(ws + 202506240);
  ushort_t* Wiox = (ushort_t*)(ws + 204603392);
  ushort_t* Wioh = (ushort_t*)(ws + 205127680);
  ushort_t* Wo1  = (ushort_t*)(ws + 206176256);
  ushort_t* Wo2  = (ushort_t*)(ws + 206700544);

  hipLaunchKernelGGL(init_kernel, dim3(128), dim3(256), 0, stream, (uint32_t*)Harr);
  hipLaunchKernelGGL(pack_kernel, dim3(77826), dim3(256), 0, stream,
                     x, W_i2h, W_i2o, W_o2o, b_i2o, b_o2o,
                     xB, Wihx, Whh, Wiox, Wioh, Wo1, Wo2, biasP);
  hipLaunchKernelGGL(gemm_bt, dim3(2048), dim3(256), 0, stream,
                     xB, 512, Wihx, 512, b_i2h, XhB, 8);
  hipLaunchKernelGGL(usetup_kernel, dim3(48), dim3(256), 0, stream,
                     Wo1, Wiox, Wioh, U1, U2);
  // pass1 k=1..7 with power ride-alongs (extra blocks beyond 512)
  const int extraP[8] = {0, 64, 128, 256, 64, 64, 64, 64};  // per mode 1..7
  for (int k = 1; k <= 7; ++k) {
    const ushort_t* A = (k == 1) ? XhB : (Harr + (size_t)k * 65536);
    hipLaunchKernelGGL(step_pow, dim3(512 + extraP[k]), dim3(256), 0, stream,
                       A, XhB + (size_t)k * 65536, Harr + (size_t)(k + 1) * 65536,
                       Whh, Pw, k);
  }
  // W256 (power-only launch)
  hipLaunchKernelGGL(step_pow, dim3(64), dim3(256), 0, stream,
                     Whh, Whh, (ushort_t*)Harr, Whh, Pw, 8);
  // Hillis-Steele scan over chunk starts (final S lands in SA)
  hipLaunchKernelGGL(scan64, dim3(512), dim3(256), 0, stream, Harr, SB, Pw + 6 * 1048576, 1);
  hipLaunchKernelGGL(scan64, dim3(512), dim3(256), 0, stream, SB, SA, Pw + 7 * 1048576, 2);
  hipLaunchKernelGGL(scan64, dim3(512), dim3(256), 0, stream, SA, SB, Pw + 8 * 1048576, 4);
  hipLaunchKernelGGL(scan64, dim3(512), dim3(256), 0, stream, SB, SA, Pw + 9 * 1048576, 8);
  hipLaunchKernelGGL(scan64, dim3(512), dim3(256), 0, stream, SA, SB, Pw + 10 * 1048576, 16);
  hipLaunchKernelGGL(scan64, dim3(512), dim3(256), 0, stream, SB, SA, Pw + 11 * 1048576, 32);
  // correction: Harr[slot j][c] = X_j + S_c @ (W^j)^T, j=1..8
  hipLaunchKernelGGL(correct_kernel, dim3(dim3(256, 8)), dim3(256), 0, stream,
                     SA, XhB, Harr, Whh, Pw);
  // oc = xB@U1^T + Hprev@U2^T + Hnew@Wo2^T + bias', *mask -> d_out
  hipLaunchKernelGGL(gemm_fused, dim3(1024), dim3(256), 0, stream,
                     xB, U1, Harr, U2, Wo2, biasP, mask, out);
  hipLaunchKernelGGL(softmax_kernel, dim3(32768), dim3(256), 0, stream, out);
}